// Round 1
// baseline (127.597 us; speedup 1.0000x reference)
//
#include <hip/hip_runtime.h>

#define TT 512
#define DD 256
#define BB 2
#define MM (BB*TT)   // 1024

// ---------------------------------------------------------------------------
// GEMM: O = rowmix(X) @ W^T.  blockIdx.z selects one of up to 3 weight sets.
// MIX:    apply RWKV time-mix (x*mix + x_prev*(1-mix)) while staging X rows.
// TSTORE: store transposed as (B, D, T) [feeds the wkv scan]; mat==2 also gets
//         sigmoid applied (that matrix is r).  Else store (M, D) row-major.
// Tile: 64x64 output per block, K in 4 chunks of 64, 256 thr, 4x4 microtile.
// ---------------------------------------------------------------------------
template<bool MIX, bool TSTORE>
__global__ __launch_bounds__(256)
void gemm_kernel(const float* __restrict__ X,
                 const float* __restrict__ Xlast,
                 const float* __restrict__ W0, const float* __restrict__ W1,
                 const float* __restrict__ W2,
                 const float* __restrict__ mx0, const float* __restrict__ mx1,
                 const float* __restrict__ mx2,
                 float* __restrict__ O0, float* __restrict__ O1,
                 float* __restrict__ O2)
{
    const int mat = blockIdx.z;
    const float* W  = (mat == 0) ? W0  : (mat == 1) ? W1  : W2;
    const float* mx = (mat == 0) ? mx0 : (mat == 1) ? mx1 : mx2;
    float*       O  = (mat == 0) ? O0  : (mat == 1) ? O1  : O2;

    const int n0  = blockIdx.x * 64;
    const int m0  = blockIdx.y * 64;
    const int tid = threadIdx.x;
    const int mm  = tid & 63;   // staging row within tile
    const int q   = tid >> 6;   // staging k-quad (16 k's each)
    const int tn  = tid & 15;   // micro col group (coalesced stores)
    const int tm  = tid >> 4;   // micro row group

    const int b  = m0 / TT;     // uniform per block (64 | 512)
    const int t0 = m0 % TT;

    __shared__ float As[64][64];   // [kk][mm] transposed-in-LDS
    __shared__ float Bs[64][64];   // [kk][nn]

    float acc[4][4] = {};

    const int arow = m0 + mm;
    const int trow = t0 + mm;

    for (int k0 = 0; k0 < DD; k0 += 64) {
        #pragma unroll
        for (int i = 0; i < 4; ++i) {
            const int kk = q * 16 + i * 4;
            float4 a = *(const float4*)&X[arow * DD + k0 + kk];
            if (MIX) {
                float4 xp;
                if (trow == 0) xp = *(const float4*)&Xlast[b * DD + k0 + kk];
                else           xp = *(const float4*)&X[(arow - 1) * DD + k0 + kk];
                const float4 mv = *(const float4*)&mx[k0 + kk];
                a.x = xp.x + (a.x - xp.x) * mv.x;
                a.y = xp.y + (a.y - xp.y) * mv.y;
                a.z = xp.z + (a.z - xp.z) * mv.z;
                a.w = xp.w + (a.w - xp.w) * mv.w;
            }
            As[kk + 0][mm] = a.x;
            As[kk + 1][mm] = a.y;
            As[kk + 2][mm] = a.z;
            As[kk + 3][mm] = a.w;
            const float4 wv = *(const float4*)&W[(n0 + mm) * DD + k0 + kk];
            Bs[kk + 0][mm] = wv.x;
            Bs[kk + 1][mm] = wv.y;
            Bs[kk + 2][mm] = wv.z;
            Bs[kk + 3][mm] = wv.w;
        }
        __syncthreads();
        #pragma unroll
        for (int kk = 0; kk < 64; ++kk) {
            const float4 av = *(const float4*)&As[kk][tm * 4];
            const float4 bv = *(const float4*)&Bs[kk][tn * 4];
            const float a4[4] = {av.x, av.y, av.z, av.w};
            const float b4[4] = {bv.x, bv.y, bv.z, bv.w};
            #pragma unroll
            for (int i = 0; i < 4; ++i)
                #pragma unroll
                for (int j = 0; j < 4; ++j)
                    acc[i][j] = fmaf(a4[i], b4[j], acc[i][j]);
        }
        __syncthreads();
    }

    if (!TSTORE) {
        #pragma unroll
        for (int i = 0; i < 4; ++i) {
            float4 o = make_float4(acc[i][0], acc[i][1], acc[i][2], acc[i][3]);
            *(float4*)&O[(m0 + tm * 4 + i) * DD + n0 + tn * 4] = o;
        }
    } else {
        #pragma unroll
        for (int j = 0; j < 4; ++j) {
            float4 o = make_float4(acc[0][j], acc[1][j], acc[2][j], acc[3][j]);
            if (MIX && mat == 2) {   // r -> sigmoid(r)
                o.x = __builtin_amdgcn_rcpf(1.0f + __expf(-o.x));
                o.y = __builtin_amdgcn_rcpf(1.0f + __expf(-o.y));
                o.z = __builtin_amdgcn_rcpf(1.0f + __expf(-o.z));
                o.w = __builtin_amdgcn_rcpf(1.0f + __expf(-o.w));
            }
            const int n = n0 + tn * 4 + j;
            *(float4*)&O[((size_t)b * DD + n) * TT + t0 + tm * 4] = o;
        }
    }
}

// ---------------------------------------------------------------------------
// WKV recurrence.  8 blocks x 64 lanes; lane = one (b,d) channel.
// Inputs kT/vT/sT are (B, D, T) so each lane loads float4 along T.
// Groups of 16 timesteps, 4 register buffers, depth-3 prefetch rotation.
// Also emits the x_last / num_last / den_last tail outputs.
// ---------------------------------------------------------------------------
struct G4 { float4 k[4], v[4], s[4]; };

__device__ __forceinline__ void load_g(G4& gb, const float* kp, const float* vp,
                                       const float* sp, int g)
{
    if (g < TT / 16) {
        const int t = g * 16;
        #pragma unroll
        for (int i = 0; i < 4; ++i) {
            gb.k[i] = *(const float4*)(kp + t + 4 * i);
            gb.v[i] = *(const float4*)(vp + t + 4 * i);
            gb.s[i] = *(const float4*)(sp + t + 4 * i);
        }
    }
}

__device__ __forceinline__ void step1(float kc, float vc, float sc, int t,
                                      float& num, float& den, float ew, float eu,
                                      float* yp)
{
    const float ek  = __expf(kc);
    const float euk = eu * ek;
    const float wkv = (num + euk * vc) * __builtin_amdgcn_rcpf(den + euk);
    yp[t * DD] = wkv * sc;
    num = fmaf(ew, num, ek * vc);
    den = fmaf(ew, den, ek);
}

__device__ __forceinline__ void comp_g(const G4& gb, int g, float& num, float& den,
                                       float ew, float eu, float* yp)
{
    const int tb = g * 16;
    #pragma unroll
    for (int i = 0; i < 4; ++i) {
        step1(gb.k[i].x, gb.v[i].x, gb.s[i].x, tb + 4 * i + 0, num, den, ew, eu, yp);
        step1(gb.k[i].y, gb.v[i].y, gb.s[i].y, tb + 4 * i + 1, num, den, ew, eu, yp);
        step1(gb.k[i].z, gb.v[i].z, gb.s[i].z, tb + 4 * i + 2, num, den, ew, eu, yp);
        step1(gb.k[i].w, gb.v[i].w, gb.s[i].w, tb + 4 * i + 3, num, den, ew, eu, yp);
    }
}

__global__ __launch_bounds__(64, 1)
void wkv_kernel(const float* __restrict__ kT, const float* __restrict__ vT,
                const float* __restrict__ sT, const float* __restrict__ x,
                const float* __restrict__ last_num, const float* __restrict__ last_den,
                const float* __restrict__ time_decay, const float* __restrict__ time_first,
                float* __restrict__ y, float* __restrict__ out)
{
    const int bid = blockIdx.x;        // 0..7
    const int b   = bid >> 2;
    const int d   = ((bid & 3) << 6) + threadIdx.x;
    const int ch  = b * DD + d;

    // tail output: x[:, -1, :]
    out[MM * DD + ch] = x[(b * TT + TT - 1) * DD + d];

    const float w  = -__expf(time_decay[d]);
    const float ew = __expf(w);
    const float eu = __expf(time_first[d]);
    float num = last_num[ch];
    float den = last_den[ch];

    const float* kp = kT + (size_t)ch * TT;
    const float* vp = vT + (size_t)ch * TT;
    const float* sp = sT + (size_t)ch * TT;
    float*       yp = y + (size_t)(b * TT) * DD + d;

    G4 A, B_, C, D_;
    load_g(A,  kp, vp, sp, 0);
    load_g(B_, kp, vp, sp, 1);
    load_g(C,  kp, vp, sp, 2);

    for (int g = 0; g < TT / 16; g += 4) {
        load_g(D_, kp, vp, sp, g + 3);
        comp_g(A, g, num, den, ew, eu, yp);
        load_g(A, kp, vp, sp, g + 4);
        comp_g(B_, g + 1, num, den, ew, eu, yp);
        load_g(B_, kp, vp, sp, g + 5);
        comp_g(C, g + 2, num, den, ew, eu, yp);
        load_g(C, kp, vp, sp, g + 6);
        comp_g(D_, g + 3, num, den, ew, eu, yp);
    }

    // tail outputs: num[:, -1, :], den[:, -1, :]
    out[MM * DD + BB * DD + ch]     = num;
    out[MM * DD + 2 * BB * DD + ch] = den;
}

// ---------------------------------------------------------------------------
extern "C" void kernel_launch(void* const* d_in, const int* in_sizes, int n_in,
                              void* d_out, int out_size, void* d_ws, size_t ws_size,
                              hipStream_t stream)
{
    const float* x    = (const float*)d_in[0];
    const float* lx   = (const float*)d_in[1];
    const float* lnum = (const float*)d_in[2];
    const float* lden = (const float*)d_in[3];
    const float* td   = (const float*)d_in[4];
    const float* tf   = (const float*)d_in[5];
    const float* mk   = (const float*)d_in[6];
    const float* mv   = (const float*)d_in[7];
    const float* mr   = (const float*)d_in[8];
    const float* Wk   = (const float*)d_in[9];
    const float* Wv   = (const float*)d_in[10];
    const float* Wr   = (const float*)d_in[11];
    const float* Wo   = (const float*)d_in[12];
    float* out = (float*)d_out;

    float* kT = (float*)d_ws;          // (B, D, T)
    float* vT = kT + MM * DD;
    float* sT = vT + MM * DD;
    float* y  = sT + MM * DD;          // (B, T, D) = wkv * sigmoid(r)

    // 1) k, v, sigmoid(r) via mixed GEMMs, stored transposed for the scan
    gemm_kernel<true, true><<<dim3(4, 16, 3), 256, 0, stream>>>(
        x, lx, Wk, Wv, Wr, mk, mv, mr, kT, vT, sT);

    // 2) WKV linear recurrence + tail outputs
    wkv_kernel<<<dim3(8), 64, 0, stream>>>(
        kT, vT, sT, x, lnum, lden, td, tf, y, out);

    // 3) out = y @ Wo^T
    gemm_kernel<false, false><<<dim3(4, 16, 1), 256, 0, stream>>>(
        y, nullptr, Wo, Wo, Wo, nullptr, nullptr, nullptr, out, out, out);
}

// Round 2
// 112.848 us; speedup vs baseline: 1.1307x; 1.1307x over previous
//
#include <hip/hip_runtime.h>

#define TT 512
#define DD 256
#define BB 2
#define MM (BB*TT)          // 1024
#define LCH 16              // wkv chunk length
#define NCH (TT/LCH)        // 32 chunks per channel

// ---------------------------------------------------------------------------
// K1: k/v/r = timemix(X) @ W^T, stored TRANSPOSED as (B, D, T) for the scan.
// Tile 64(m=T) x 32(n), 128 threads, 4x4 microtile, K-chunks of 64.
// Staging is coalesced (16 lanes x 256B rows) with LDS transpose; pads 68/36
// keep inner ds_read_b128 16B-aligned.  r is stored RAW (sigmoid in K2).
// ---------------------------------------------------------------------------
__global__ __launch_bounds__(128)
void gemm_mix_t(const float* __restrict__ X, const float* __restrict__ Xlast,
                const float* __restrict__ W0, const float* __restrict__ W1,
                const float* __restrict__ W2,
                const float* __restrict__ mx0, const float* __restrict__ mx1,
                const float* __restrict__ mx2,
                float* __restrict__ O0, float* __restrict__ O1,
                float* __restrict__ O2)
{
    const int mat = blockIdx.z;
    const float* W  = (mat == 0) ? W0  : (mat == 1) ? W1  : W2;
    const float* mx = (mat == 0) ? mx0 : (mat == 1) ? mx1 : mx2;
    float*       O  = (mat == 0) ? O0  : (mat == 1) ? O1  : O2;

    const int n0  = blockIdx.x * 32;
    const int m0  = blockIdx.y * 64;
    const int b   = m0 / TT;
    const int t0  = m0 % TT;
    const int tid = threadIdx.x;

    const int cc = (tid & 15) * 4;   // k offset within chunk (staging)
    const int r8 = tid >> 4;         // 0..7
    const int tm = tid >> 3;         // 0..15 (m groups of 4)
    const int tn = tid & 7;          // 0..7  (n groups of 4)

    __shared__ float As[64][68];     // [k][m], pad 68 (16B-aligned rows)
    __shared__ float Bs[64][36];     // [k][n], pad 36

    float acc[4][4] = {};

    for (int k0 = 0; k0 < DD; k0 += 64) {
        // stage A: 64 rows (t), 64 k, coalesced, mix applied
        #pragma unroll
        for (int i = 0; i < 8; ++i) {
            const int rr  = r8 + i * 8;
            const int row = m0 + rr;
            const float4 xc = *(const float4*)&X[row * DD + k0 + cc];
            float4 xp;
            if (t0 + rr == 0) xp = *(const float4*)&Xlast[b * DD + k0 + cc];
            else              xp = *(const float4*)&X[(row - 1) * DD + k0 + cc];
            const float4 mv = *(const float4*)&mx[k0 + cc];
            As[cc + 0][rr] = xp.x + (xc.x - xp.x) * mv.x;
            As[cc + 1][rr] = xp.y + (xc.y - xp.y) * mv.y;
            As[cc + 2][rr] = xp.z + (xc.z - xp.z) * mv.z;
            As[cc + 3][rr] = xp.w + (xc.w - xp.w) * mv.w;
        }
        // stage B: 32 rows of W, 64 k, coalesced
        #pragma unroll
        for (int i = 0; i < 4; ++i) {
            const int rr = r8 + i * 8;
            const float4 wv = *(const float4*)&W[(n0 + rr) * DD + k0 + cc];
            Bs[cc + 0][rr] = wv.x;
            Bs[cc + 1][rr] = wv.y;
            Bs[cc + 2][rr] = wv.z;
            Bs[cc + 3][rr] = wv.w;
        }
        __syncthreads();
        #pragma unroll
        for (int kk = 0; kk < 64; ++kk) {
            const float4 a4 = *(const float4*)&As[kk][tm * 4];
            const float4 b4 = *(const float4*)&Bs[kk][tn * 4];
            const float am[4] = {a4.x, a4.y, a4.z, a4.w};
            const float bn[4] = {b4.x, b4.y, b4.z, b4.w};
            #pragma unroll
            for (int i = 0; i < 4; ++i)
                #pragma unroll
                for (int j = 0; j < 4; ++j)
                    acc[i][j] = fmaf(am[i], bn[j], acc[i][j]);
        }
        __syncthreads();
    }

    // store transposed: O[(b, n, t)] ; t = t0 + tm*4 + i, n = n0 + tn*4 + j
    #pragma unroll
    for (int j = 0; j < 4; ++j) {
        const float4 o = make_float4(acc[0][j], acc[1][j], acc[2][j], acc[3][j]);
        *(float4*)&O[(size_t)(b * DD + n0 + tn * 4 + j) * TT + t0 + tm * 4] = o;
    }
}

// ---------------------------------------------------------------------------
// K2: WKV via chunked parallel scan.  64 blocks x 256 thr.
// Thread = (channel, chunk): ch = bid*8 + (tid>>5), chunk = tid&31 (L=16).
// Local Horner sums -> shfl_up scan over 32 chunks -> replay 16 steps.
// Also: zeroes nothing, writes yT (B,D,T), tail outputs, applies sigmoid(r).
// ---------------------------------------------------------------------------
__global__ __launch_bounds__(256)
void wkv_scan(const float* __restrict__ kT, const float* __restrict__ vT,
              const float* __restrict__ rT, const float* __restrict__ x,
              const float* __restrict__ last_num, const float* __restrict__ last_den,
              const float* __restrict__ time_decay, const float* __restrict__ time_first,
              float* __restrict__ yT, float* __restrict__ out)
{
    const int tid  = threadIdx.x;
    const int ch   = blockIdx.x * 8 + (tid >> 5);
    const int lane = tid & 31;           // chunk index
    const int b    = ch >> 8;
    const int d    = ch & (DD - 1);

    const float w  = -__expf(time_decay[d]);
    const float ew = __expf(w);
    const float eu = __expf(time_first[d]);

    const size_t base = (size_t)ch * TT + lane * LCH;
    float k_[LCH], v_[LCH], r_[LCH];
    #pragma unroll
    for (int i = 0; i < 4; ++i) {
        *(float4*)&k_[4 * i] = *(const float4*)(kT + base + 4 * i);
        *(float4*)&v_[4 * i] = *(const float4*)(vT + base + 4 * i);
        *(float4*)&r_[4 * i] = *(const float4*)(rT + base + 4 * i);
    }

    float ek[LCH], ekv[LCH], sr[LCH];
    #pragma unroll
    for (int i = 0; i < LCH; ++i) {
        ek[i]  = __expf(k_[i]);
        ekv[i] = ek[i] * v_[i];
        sr[i]  = __builtin_amdgcn_rcpf(1.0f + __expf(-r_[i]));
    }

    // chunk-local: A = ew^L, B = sum_i ew^(L-1-i) * (ekv | ek)
    float A = __expf(w * (float)LCH);
    float Bn = 0.0f, Bd = 0.0f;
    #pragma unroll
    for (int i = 0; i < LCH; ++i) {
        Bn = fmaf(ew, Bn, ekv[i]);
        Bd = fmaf(ew, Bd, ek[i]);
    }

    // inclusive scan over 32 chunks (width-32 segments of the wave)
    #pragma unroll
    for (int s = 1; s < 32; s <<= 1) {
        const float Ax  = __shfl_up(A, s, 32);
        const float Bnx = __shfl_up(Bn, s, 32);
        const float Bdx = __shfl_up(Bd, s, 32);
        if (lane >= s) {
            Bn = fmaf(A, Bnx, Bn);
            Bd = fmaf(A, Bdx, Bd);
            A *= Ax;
        }
    }

    // exclusive state entering this chunk
    float Aex  = __shfl_up(A, 1, 32);
    float Bnex = __shfl_up(Bn, 1, 32);
    float Bdex = __shfl_up(Bd, 1, 32);
    if (lane == 0) { Aex = 1.0f; Bnex = 0.0f; Bdex = 0.0f; }
    float sn = fmaf(Aex, last_num[ch], Bnex);
    float sd = fmaf(Aex, last_den[ch], Bdex);

    // replay 16 steps
    float y_[LCH];
    #pragma unroll
    for (int i = 0; i < LCH; ++i) {
        const float euk = eu * ek[i];
        const float wkv = (sn + eu * ekv[i]) * __builtin_amdgcn_rcpf(sd + euk);
        y_[i] = wkv * sr[i];
        sn = fmaf(ew, sn, ekv[i]);
        sd = fmaf(ew, sd, ek[i]);
    }
    #pragma unroll
    for (int i = 0; i < 4; ++i)
        *(float4*)(yT + base + 4 * i) = *(const float4*)&y_[4 * i];

    // tails: x_last from lane 0; num/den last from lane 31 (inclusive state)
    if (lane == 31) {
        out[MM * DD + BB * DD + ch]     = sn;
        out[MM * DD + 2 * BB * DD + ch] = sd;
    }
    if (lane == 0)
        out[MM * DD + ch] = x[(b * TT + TT - 1) * DD + d];
}

// ---------------------------------------------------------------------------
// K3: out = yT^T @ Wo^T.  A comes pre-transposed (B,D,T) -> direct b128 LDS
// stage.  Tile 32(m=T) x 32(n), 64 threads (1 wave), 4x4 micro, 256 blocks.
// ---------------------------------------------------------------------------
__global__ __launch_bounds__(64)
void gemm_out(const float* __restrict__ yT, const float* __restrict__ Wo,
              float* __restrict__ O)
{
    const int n0  = blockIdx.x * 32;
    const int m0  = blockIdx.y * 32;
    const int b   = m0 >> 9;            // /TT
    const int t0  = m0 & (TT - 1);
    const int tid = threadIdx.x;

    __shared__ float As[64][36];        // [k][m(t)], pad 36
    __shared__ float Bs[64][36];        // [k][n]

    const int tm = tid >> 3;            // 0..7
    const int tn = tid & 7;             // 0..7

    float acc[4][4] = {};

    for (int k0 = 0; k0 < DD; k0 += 64) {
        // stage A: direct copy from (D,T) layout, b128 LDS writes
        {
            const int mq = (tid & 7) * 4;
            #pragma unroll
            for (int i = 0; i < 8; ++i) {
                const int kk = (tid >> 3) + i * 8;
                *(float4*)&As[kk][mq] =
                    *(const float4*)&yT[(size_t)(b * DD + k0 + kk) * TT + t0 + mq];
            }
        }
        // stage B: coalesced rows of Wo, transpose into LDS
        {
            const int cc = (tid & 15) * 4;
            #pragma unroll
            for (int i = 0; i < 8; ++i) {
                const int rr = (tid >> 4) + i * 4;   // 0..31
                const float4 wv = *(const float4*)&Wo[(n0 + rr) * DD + k0 + cc];
                Bs[cc + 0][rr] = wv.x;
                Bs[cc + 1][rr] = wv.y;
                Bs[cc + 2][rr] = wv.z;
                Bs[cc + 3][rr] = wv.w;
            }
        }
        __syncthreads();
        #pragma unroll
        for (int kk = 0; kk < 64; ++kk) {
            const float4 a4 = *(const float4*)&As[kk][tm * 4];
            const float4 b4 = *(const float4*)&Bs[kk][tn * 4];
            const float am[4] = {a4.x, a4.y, a4.z, a4.w};
            const float bn[4] = {b4.x, b4.y, b4.z, b4.w};
            #pragma unroll
            for (int i = 0; i < 4; ++i)
                #pragma unroll
                for (int j = 0; j < 4; ++j)
                    acc[i][j] = fmaf(am[i], bn[j], acc[i][j]);
        }
        __syncthreads();
    }

    #pragma unroll
    for (int i = 0; i < 4; ++i) {
        const float4 o = make_float4(acc[i][0], acc[i][1], acc[i][2], acc[i][3]);
        *(float4*)&O[(size_t)(m0 + tm * 4 + i) * DD + n0 + tn * 4] = o;
    }
}

// ---------------------------------------------------------------------------
extern "C" void kernel_launch(void* const* d_in, const int* in_sizes, int n_in,
                              void* d_out, int out_size, void* d_ws, size_t ws_size,
                              hipStream_t stream)
{
    const float* x    = (const float*)d_in[0];
    const float* lx   = (const float*)d_in[1];
    const float* lnum = (const float*)d_in[2];
    const float* lden = (const float*)d_in[3];
    const float* td   = (const float*)d_in[4];
    const float* tf   = (const float*)d_in[5];
    const float* mk   = (const float*)d_in[6];
    const float* mv   = (const float*)d_in[7];
    const float* mr   = (const float*)d_in[8];
    const float* Wk   = (const float*)d_in[9];
    const float* Wv   = (const float*)d_in[10];
    const float* Wr   = (const float*)d_in[11];
    const float* Wo   = (const float*)d_in[12];
    float* out = (float*)d_out;

    float* kT = (float*)d_ws;          // (B, D, T)
    float* vT = kT + MM * DD;
    float* rT = vT + MM * DD;          // raw r (sigmoid applied in K2)
    float* yT = rT + MM * DD;          // (B, D, T) = wkv * sigmoid(r)

    gemm_mix_t<<<dim3(8, 16, 3), 128, 0, stream>>>(
        x, lx, Wk, Wv, Wr, mk, mv, mr, kT, vT, rT);

    wkv_scan<<<dim3(64), 256, 0, stream>>>(
        kT, vT, rT, x, lnum, lden, td, tf, yT, out);

    gemm_out<<<dim3(8, 32), 64, 0, stream>>>(yT, Wo, out);
}